// Round 1
// baseline (1404.501 us; speedup 1.0000x reference)
//
#include <hip/hip_runtime.h>
#include <math.h>

#define ETA 0.1f

// Taylor coefficients 1/k!
#define C0 1.0f
#define C1 1.0f
#define C2 0.5f
#define C3 (1.0f/6.0f)
#define C4 (1.0f/24.0f)
#define C5 (1.0f/120.0f)
#define C6 (1.0f/720.0f)
#define C7 (1.0f/5040.0f)
#define C8 (1.0f/40320.0f)
#define C9 (1.0f/362880.0f)

// Swizzled LDS address (in floats) for 64x64 fp32 matrix stored as 16 chunks
// of 4 floats per row. Chunk index XOR'd with row keeps ds_read_b128 16B
// alignment and caps bank conflicts at 2-way (free) without padding.
__device__ __forceinline__ int swz(int r, int cc) {
    return r * 64 + 4 * (cc ^ (r & 15));
}

// C = X*Y + cI*I + cB*Bm   (all in LDS, swizzled layout)
// Thread (tx,ty) owns rows 4*ty..+3, cols 4*tx..+3.
__device__ __forceinline__ void mm64(const float* X, const float* Y, float* C,
                                     const float* Bm, float cI, float cB,
                                     int tx, int ty) {
    float acc[4][4] = {{0.f}};
#pragma unroll 4
    for (int k0 = 0; k0 < 64; k0 += 4) {
        float a[4][4], bb[4][4];
#pragma unroll
        for (int i = 0; i < 4; ++i) {
            float4 t = *(const float4*)&X[swz(4 * ty + i, k0 >> 2)];
            a[i][0] = t.x; a[i][1] = t.y; a[i][2] = t.z; a[i][3] = t.w;
        }
#pragma unroll
        for (int k = 0; k < 4; ++k) {
            float4 t = *(const float4*)&Y[swz(k0 + k, tx)];
            bb[k][0] = t.x; bb[k][1] = t.y; bb[k][2] = t.z; bb[k][3] = t.w;
        }
#pragma unroll
        for (int i = 0; i < 4; ++i)
#pragma unroll
            for (int k = 0; k < 4; ++k)
#pragma unroll
                for (int j = 0; j < 4; ++j)
                    acc[i][j] = fmaf(a[i][k], bb[k][j], acc[i][j]);
    }
#pragma unroll
    for (int i = 0; i < 4; ++i) {
        int r = 4 * ty + i;
        float4 bm = *(const float4*)&Bm[swz(r, tx)];
        float bmv[4] = {bm.x, bm.y, bm.z, bm.w};
        float4 o;
        float* ov = (float*)&o;
#pragma unroll
        for (int j = 0; j < 4; ++j) {
            float v = fmaf(cB, bmv[j], acc[i][j]);
            if (4 * tx + j == r) v += cI;
            ov[j] = v;
        }
        *(float4*)&C[swz(r, tx)] = o;
    }
}

__global__ __launch_bounds__(256) void meg_expm_kernel(
    const float* __restrict__ Rg, const float* __restrict__ Gg,
    float* __restrict__ out) {
    __shared__ float Bm[4096];
    __shared__ float B2[4096];
    __shared__ float T1[4096];
    __shared__ float T2[4096];

    const int t = threadIdx.x;
    const int tx = t & 15;
    const int ty = t >> 4;
    const long long base = (long long)blockIdx.x * 4096;

    // ---- stage grad into T1 (coalesced float4 loads) ----
#pragma unroll
    for (int i = 0; i < 4; ++i) {
        int idx = t + i * 256;            // float4 index 0..1023
        int r = idx >> 4, cc = idx & 15;
        float4 g = ((const float4*)(Gg + base))[idx];
        *(float4*)&T1[swz(r, cc)] = g;
    }
    __syncthreads();

    // ---- A = log(R) - ETA*(G - G^T) -> Bm ----
#pragma unroll
    for (int i = 0; i < 4; ++i) {
        int r = 4 * ty + i;
        float4 rv = *(const float4*)&Rg[base + r * 64 + 4 * tx];
        float4 gv = *(const float4*)&T1[swz(r, tx)];
        float gt[4];
#pragma unroll
        for (int j = 0; j < 4; ++j) {
            int c = 4 * tx + j;
            gt[j] = T1[swz(c, r >> 2) + (r & 3)];   // G[c][r]
        }
        float4 o;
        o.x = logf(rv.x) - ETA * (gv.x - gt[0]);
        o.y = logf(rv.y) - ETA * (gv.y - gt[1]);
        o.z = logf(rv.z) - ETA * (gv.z - gt[2]);
        o.w = logf(rv.w) - ETA * (gv.w - gt[3]);
        *(float4*)&Bm[swz(r, tx)] = o;
    }
    __syncthreads();

    // ---- 1-norm (max abs column sum) by wave 0; broadcast s via T2[0] ----
    if (t < 64) {
        float csum = 0.f;
        for (int r = 0; r < 64; ++r)
            csum += fabsf(Bm[swz(r, t >> 2) + (t & 3)]);
#pragma unroll
        for (int off = 32; off >= 1; off >>= 1)
            csum = fmaxf(csum, __shfl_xor(csum, off));
        if (t == 0) {
            int s = 0;
            if (csum > 1.0f) {
                s = (int)ceilf(log2f(csum));
                if (s > 30) s = 30;
            }
            T2[0] = (float)s;
        }
    }
    __syncthreads();
    const int s = (int)T2[0];
    const float scale = exp2f(-(float)s);

    // ---- scale Bm in place (each thread scales the chunks it wrote) ----
#pragma unroll
    for (int i = 0; i < 4; ++i) {
        int r = 4 * ty + i;
        float4* p = (float4*)&Bm[swz(r, tx)];
        float4 v = *p;
        v.x *= scale; v.y *= scale; v.z *= scale; v.w *= scale;
        *p = v;
    }
    __syncthreads();   // all read T2[0] & scaled Bm visible before reuse of T2

    // ---- B2 = Bm*Bm ----
    mm64(Bm, Bm, B2, Bm, 0.f, 0.f, tx, ty);
    __syncthreads();

    // ---- T2 = C8*I + C9*Bm ----
#pragma unroll
    for (int i = 0; i < 4; ++i) {
        int r = 4 * ty + i;
        float4 bm = *(const float4*)&Bm[swz(r, tx)];
        float4 o;
        o.x = C9 * bm.x; o.y = C9 * bm.y; o.z = C9 * bm.z; o.w = C9 * bm.w;
        if (r >= 4 * tx && r < 4 * tx + 4) ((float*)&o)[r - 4 * tx] += C8;
        *(float4*)&T2[swz(r, tx)] = o;
    }
    __syncthreads();

    // ---- Paterson-Stockmeyer Horner in B2 (degree-9 Taylor) ----
    mm64(T2, B2, T1, Bm, C6, C7, tx, ty); __syncthreads();
    mm64(T1, B2, T2, Bm, C4, C5, tx, ty); __syncthreads();
    mm64(T2, B2, T1, Bm, C2, C3, tx, ty); __syncthreads();
    mm64(T1, B2, T2, Bm, C0, C1, tx, ty); __syncthreads();

    // ---- s squarings, ping-pong T2 <-> T1 ----
    const float* cur = T2;
    float* oth = T1;
    for (int it = 0; it < s; ++it) {
        mm64(cur, cur, oth, Bm, 0.f, 0.f, tx, ty);
        __syncthreads();
        float* tmp = (float*)cur; cur = oth; oth = tmp;
    }

    // ---- store (coalesced float4) ----
#pragma unroll
    for (int i = 0; i < 4; ++i) {
        int r = 4 * ty + i;
        float4 v = *(const float4*)&cur[swz(r, tx)];
        *(float4*)&out[base + r * 64 + 4 * tx] = v;
    }
}

extern "C" void kernel_launch(void* const* d_in, const int* in_sizes, int n_in,
                              void* d_out, int out_size, void* d_ws, size_t ws_size,
                              hipStream_t stream) {
    const float* R = (const float*)d_in[0];
    const float* G = (const float*)d_in[1];
    float* out = (float*)d_out;
    const int B = in_sizes[0] / (64 * 64);   // 8192
    meg_expm_kernel<<<dim3(B), dim3(256), 0, stream>>>(R, G, out);
}

// Round 2
// 582.087 us; speedup vs baseline: 2.4129x; 2.4129x over previous
//
#include <hip/hip_runtime.h>
#include <math.h>

#define ETA 0.1f

#define C0 1.0f
#define C1 1.0f
#define C2 0.5f
#define C3 (1.0f/6.0f)
#define C4 (1.0f/24.0f)
#define C5 (1.0f/120.0f)
#define C6 (1.0f/720.0f)
#define C7 (1.0f/5040.0f)
#define C8 (1.0f/40320.0f)
#define C9 (1.0f/362880.0f)

typedef __attribute__((ext_vector_type(8))) short short8;
typedef __attribute__((ext_vector_type(4))) float f32x4;

// fp32 staging buffer swizzle (16 float4-chunks per row, XOR by row) — round-1 proven
__device__ __forceinline__ int swzF(int r, int cc) { return r * 64 + 4 * (cc ^ (r & 15)); }

// bf16 row-major layout (ushort units): row r, col c. 8 chunks of 8 per row,
// chunk index XOR'd with r&7 -> b128 reads stay 16B aligned, banks spread.
__device__ __forceinline__ int rmI(int r, int c) {
    return r * 64 + 8 * ((c >> 3) ^ (r & 7)) + (c & 7);
}
// bf16 col-major layout: col c major, row r minor; chunk XOR with c&7.
__device__ __forceinline__ int cmI(int r, int c) {
    return c * 64 + 8 * ((r >> 3) ^ (c & 7)) + (r & 7);
}

// split fp32 -> bf16 hi (RNE) + bf16 lo (trunc of residual); x ~= hi + lo to ~2^-17
__device__ __forceinline__ void splitbf(float x, unsigned short& h, unsigned short& l) {
    unsigned u = __float_as_uint(x);
    unsigned r = u + 0x7FFFu + ((u >> 16) & 1u);
    h = (unsigned short)(r >> 16);
    float d = x - __uint_as_float(r & 0xFFFF0000u);
    l = (unsigned short)(__float_as_uint(d) >> 16);
}
__device__ __forceinline__ float bf2f(unsigned short h) {
    return __uint_as_float(((unsigned)h) << 16);
}

// One 64x64 matmul stage on MFMA: C = A*B (+ cI*I + cB*Bm), split-bf16 4 products.
// A from row-major h/l (rmI), B from col-major h/l (cmI).
// Output written to col-major h/l (Oh/Ol) and/or row-major h/l (ORh/ORl).
// Mid-barrier separates all reads from all writes (needed when out aliases in).
__device__ __forceinline__ void mmstage(
    const unsigned short* Ah, const unsigned short* Al,
    const unsigned short* Bh, const unsigned short* Bl,
    unsigned short* Oh, unsigned short* Ol,
    unsigned short* ORh, unsigned short* ORl,
    const unsigned short* BmH, const unsigned short* BmL,
    float cI, float cB, int wv, int lane)
{
    const int n16 = lane & 15;
    const int q = lane >> 4;           // 0..3
    const int mrow = 16 * wv + n16;    // A-operand row for this lane

    short8 ah[2], al[2], bh[4][2], bl[4][2];
#pragma unroll
    for (int ks = 0; ks < 2; ++ks) {
        int k0 = 32 * ks + 8 * q;
        int ia = rmI(mrow, k0);
        ah[ks] = *(const short8*)(Ah + ia);
        al[ks] = *(const short8*)(Al + ia);
#pragma unroll
        for (int t4 = 0; t4 < 4; ++t4) {
            int ib = cmI(k0, 16 * t4 + n16);
            bh[t4][ks] = *(const short8*)(Bh + ib);
            bl[t4][ks] = *(const short8*)(Bl + ib);
        }
    }

    f32x4 acc[4] = {{0.f,0.f,0.f,0.f},{0.f,0.f,0.f,0.f},{0.f,0.f,0.f,0.f},{0.f,0.f,0.f,0.f}};
#pragma unroll
    for (int ks = 0; ks < 2; ++ks) {
#pragma unroll
        for (int t4 = 0; t4 < 4; ++t4)
            acc[t4] = __builtin_amdgcn_mfma_f32_16x16x32_bf16(ah[ks], bh[t4][ks], acc[t4], 0, 0, 0);
#pragma unroll
        for (int t4 = 0; t4 < 4; ++t4)
            acc[t4] = __builtin_amdgcn_mfma_f32_16x16x32_bf16(al[ks], bl[t4][ks], acc[t4], 0, 0, 0);
#pragma unroll
        for (int t4 = 0; t4 < 4; ++t4)
            acc[t4] = __builtin_amdgcn_mfma_f32_16x16x32_bf16(ah[ks], bl[t4][ks], acc[t4], 0, 0, 0);
#pragma unroll
        for (int t4 = 0; t4 < 4; ++t4)
            acc[t4] = __builtin_amdgcn_mfma_f32_16x16x32_bf16(al[ks], bh[t4][ks], acc[t4], 0, 0, 0);
    }

    const int rbase = 16 * wv + 4 * q;   // C/D layout: row = 16*wv + 4*quad + reg, col = 16*t + n16
    if (BmH) {
#pragma unroll
        for (int t4 = 0; t4 < 4; ++t4) {
            int c = 16 * t4 + n16;
            int ib = cmI(rbase, c);
            const ushort4 hh = *(const ushort4*)(BmH + ib);
            const ushort4 ll = *(const ushort4*)(BmL + ib);
            float bmv[4] = { bf2f(hh.x) + bf2f(ll.x), bf2f(hh.y) + bf2f(ll.y),
                             bf2f(hh.z) + bf2f(ll.z), bf2f(hh.w) + bf2f(ll.w) };
#pragma unroll
            for (int rg = 0; rg < 4; ++rg) {
                float v = acc[t4][rg] + cB * bmv[rg];
                if (rbase + rg == c) v += cI;
                acc[t4][rg] = v;
            }
        }
    }

    __syncthreads();   // all reads done before any write (handles in/out aliasing)

#pragma unroll
    for (int t4 = 0; t4 < 4; ++t4) {
        int c = 16 * t4 + n16;
        unsigned short h[4], l[4];
#pragma unroll
        for (int rg = 0; rg < 4; ++rg) splitbf(acc[t4][rg], h[rg], l[rg]);
        if (Oh) {
            int io = cmI(rbase, c);   // 4 consecutive rows, same half-chunk -> b64
            *(ushort4*)(Oh + io) = make_ushort4(h[0], h[1], h[2], h[3]);
            *(ushort4*)(Ol + io) = make_ushort4(l[0], l[1], l[2], l[3]);
        }
        if (ORh) {
#pragma unroll
            for (int rg = 0; rg < 4; ++rg) {
                int io = rmI(rbase + rg, c);
                ORh[io] = h[rg];
                ORl[io] = l[rg];
            }
        }
    }
    __syncthreads();
}

__global__ __launch_bounds__(256, 2) void meg_expm_kernel(
    const float* __restrict__ Rg, const float* __restrict__ Gg,
    float* __restrict__ out)
{
    // 64 KiB LDS, carved:
    __shared__ __align__(16) unsigned short sm[32768];
    unsigned short* cm0h = sm;             // T ping  (col-major h)
    unsigned short* cm0l = sm + 4096;
    unsigned short* cm1h = sm + 8192;      // T pong
    unsigned short* cm1l = sm + 12288;
    unsigned short* bmch = sm + 16384;     // Bm col-major h  (later: squaring rm ping)
    unsigned short* bmcl = sm + 20480;
    unsigned short* rm0h = sm + 24576;     // Bm-rm -> B2-rm  (later: squaring rm pong)
    unsigned short* rm0l = sm + 28672;
    float* FB0 = (float*)sm;               // fp32 staging over cm0 (A matrix)
    float* FB1 = (float*)(sm + 8192);      // fp32 staging over cm1 (G matrix)
    float* wmax = (float*)(sm + 16384);    // 4 per-wave norm maxima (over bm area)

    const int t = threadIdx.x;
    const int wv = t >> 6, lane = t & 63;
    const int tx = t & 15, ty = t >> 4;
    const long long base = (long long)blockIdx.x * 4096;

    // ---- stage grad into FB1 (coalesced float4) ----
#pragma unroll
    for (int i = 0; i < 4; ++i) {
        int idx = t + i * 256;
        int r = idx >> 4, cc = idx & 15;
        *(float4*)&FB1[swzF(r, cc)] = ((const float4*)(Gg + base))[idx];
    }
    __syncthreads();

    // ---- A = log(R) - ETA*(G - G^T) -> FB0 (fp32, swizzled) ----
#pragma unroll
    for (int i = 0; i < 4; ++i) {
        int r = 4 * ty + i;
        float4 rv = *(const float4*)&Rg[base + r * 64 + 4 * tx];
        float4 gv = *(const float4*)&FB1[swzF(r, tx)];
        float gt[4];
#pragma unroll
        for (int j = 0; j < 4; ++j)
            gt[j] = FB1[swzF(4 * tx + j, r >> 2) + (r & 3)];   // G[c][r]
        float4 o;
        o.x = logf(rv.x) - ETA * (gv.x - gt[0]);
        o.y = logf(rv.y) - ETA * (gv.y - gt[1]);
        o.z = logf(rv.z) - ETA * (gv.z - gt[2]);
        o.w = logf(rv.w) - ETA * (gv.w - gt[3]);
        *(float4*)&FB0[swzF(r, tx)] = o;
    }
    __syncthreads();

    // ---- 1-norm: each wave sums 16 cols (4 lanes/col, 16 rows each) ----
    {
        int c = 16 * wv + (lane & 15);
        int rq = lane >> 4;
        float cs = 0.f;
#pragma unroll
        for (int rr = 0; rr < 16; ++rr) {
            int r = 16 * rq + rr;
            cs += fabsf(FB0[swzF(r, c >> 2) + (c & 3)]);
        }
        cs += __shfl_xor(cs, 16);
        cs += __shfl_xor(cs, 32);
        cs = fmaxf(cs, __shfl_xor(cs, 8));
        cs = fmaxf(cs, __shfl_xor(cs, 4));
        cs = fmaxf(cs, __shfl_xor(cs, 2));
        cs = fmaxf(cs, __shfl_xor(cs, 1));
        if (lane == 0) wmax[wv] = cs;
    }
    __syncthreads();

    const float nrm = fmaxf(fmaxf(wmax[0], wmax[1]), fmaxf(wmax[2], wmax[3]));
    int s = 0;
    if (nrm > 1.0f) {
        s = (int)ceilf(log2f(nrm));
        if (s > 30) s = 30;
        if (s < 0) s = 0;
    }
    const float scale = exp2f(-(float)s);

    // ---- read A back, scale, split; prepare Bm (h/l) and T0 = C9*Bm + C8*I ----
    unsigned short abmh[4][4], abml[4][4], t0h[4][4], t0l[4][4];
#pragma unroll
    for (int i = 0; i < 4; ++i) {
        int r = 4 * ty + i;
        float4 a = *(const float4*)&FB0[swzF(r, tx)];
        float av[4] = { a.x, a.y, a.z, a.w };
#pragma unroll
        for (int j = 0; j < 4; ++j) {
            float x = av[j] * scale;
            splitbf(x, abmh[i][j], abml[i][j]);
            float t0 = C9 * x + ((r == 4 * tx + j) ? C8 : 0.f);
            splitbf(t0, t0h[i][j], t0l[i][j]);
        }
    }
    __syncthreads();   // FB0/wmax reads done before overwrites below

    // write Bm col-major (bm area), Bm row-major (rm0 area), T0 col-major (cm0)
#pragma unroll
    for (int i = 0; i < 4; ++i) {
        int r = 4 * ty + i;
        *(ushort4*)(rm0h + rmI(r, 4 * tx)) = make_ushort4(abmh[i][0], abmh[i][1], abmh[i][2], abmh[i][3]);
        *(ushort4*)(rm0l + rmI(r, 4 * tx)) = make_ushort4(abml[i][0], abml[i][1], abml[i][2], abml[i][3]);
#pragma unroll
        for (int j = 0; j < 4; ++j) {
            int c = 4 * tx + j;
            int ic = cmI(r, c);
            bmch[ic] = abmh[i][j];
            bmcl[ic] = abml[i][j];
            cm0h[ic] = t0h[i][j];
            cm0l[ic] = t0l[i][j];
        }
    }
    __syncthreads();

    // ---- B2 = Bm*Bm -> row-major only (rm0, aliases A-source; mid-barrier guards) ----
    mmstage(rm0h, rm0l, bmch, bmcl, nullptr, nullptr, rm0h, rm0l,
            nullptr, nullptr, 0.f, 0.f, wv, lane);

    // ---- Horner (B2 and T commute): T' = B2*T + cI*I + cB*Bm ----
    mmstage(rm0h, rm0l, cm0h, cm0l, cm1h, cm1l, nullptr, nullptr, bmch, bmcl, C6, C7, wv, lane);
    mmstage(rm0h, rm0l, cm1h, cm1l, cm0h, cm0l, nullptr, nullptr, bmch, bmcl, C4, C5, wv, lane);
    mmstage(rm0h, rm0l, cm0h, cm0l, cm1h, cm1l, nullptr, nullptr, bmch, bmcl, C2, C3, wv, lane);
    // last Horner also emits row-major X0 into bm area (epilogue reads bm first; mid-barrier guards)
    mmstage(rm0h, rm0l, cm1h, cm1l, cm0h, cm0l, bmch, bmcl, bmch, bmcl, C0, C1, wv, lane);

    // ---- s squarings: X <- X*X ----
    unsigned short *ccmh = cm0h, *ccml = cm0l, *ocmh = cm1h, *ocml = cm1l;
    unsigned short *crmh = bmch, *crml = bmcl, *ormh = rm0h, *orml = rm0l;
    for (int it = 0; it < s; ++it) {
        bool lastp = (it == s - 1);
        mmstage(crmh, crml, ccmh, ccml, ocmh, ocml,
                lastp ? nullptr : ormh, lastp ? nullptr : orml,
                nullptr, nullptr, 0.f, 0.f, wv, lane);
        unsigned short* tp;
        tp = ccmh; ccmh = ocmh; ocmh = tp;
        tp = ccml; ccml = ocml; ocml = tp;
        tp = crmh; crmh = ormh; ormh = tp;
        tp = crml; crml = orml; orml = tp;
    }

    // ---- readout: reconstruct fp32 = h + l from col-major, coalesced float4 stores ----
#pragma unroll
    for (int i = 0; i < 4; ++i) {
        int g = i * 256 + t;
        int r = g >> 4, cg = g & 15;
        float ov[4];
#pragma unroll
        for (int j = 0; j < 4; ++j) {
            int c = 4 * cg + j;
            int ic = cmI(r, c);
            ov[j] = bf2f(ccmh[ic]) + bf2f(ccml[ic]);
        }
        float4 o;
        o.x = ov[0]; o.y = ov[1]; o.z = ov[2]; o.w = ov[3];
        ((float4*)(out + base))[g] = o;
    }
}

extern "C" void kernel_launch(void* const* d_in, const int* in_sizes, int n_in,
                              void* d_out, int out_size, void* d_ws, size_t ws_size,
                              hipStream_t stream) {
    const float* R = (const float*)d_in[0];
    const float* G = (const float*)d_in[1];
    float* o = (float*)d_out;
    const int B = in_sizes[0] / (64 * 64);
    meg_expm_kernel<<<dim3(B), dim3(256), 0, stream>>>(R, G, o);
}